// Round 1
// baseline (313.028 us; speedup 1.0000x reference)
//
#include <hip/hip_runtime.h>
#include <hip/hip_bf16.h>

// SEAL GCN: 3x GraphConv(norm=both) -> SumPool(graph_id sorted) -> MLP(128->128 relu ->200)
// N=50000, E=800000, feat=128, 512 graphs.
// R11: fuse gather+GEMM per layer (WF fragment-ordered weights read from L2, no Ws LDS
//      tile -> 8 blocks/CU) + fuse layer-2 gather with SumPool (LDS slot accum + ~800K
//      global fp32 atomics; kills agg fp32 roundtrip). Head reads pooled g only.

#define FEAT 128
#define NG 512
#define CH 128       // edge chunks for hist/fill
#define NPMAX 12544  // max node-quads (N<=50176); 50KB static LDS
#define LDW 136      // LDS row stride in ushorts (bf16): 2-way-free banks for b128

typedef __attribute__((ext_vector_type(8))) short bf16x8;
typedef __attribute__((ext_vector_type(4))) float f32x4;

__device__ __forceinline__ float bf2f(unsigned short u) {
    union { unsigned int i; float f; } v; v.i = ((unsigned int)u) << 16; return v.f;
}
__device__ __forceinline__ unsigned short f2bf(float f) {
    unsigned int u = __float_as_uint(f);
    return (unsigned short)((u + 0x7FFFu + ((u >> 16) & 1u)) >> 16);  // RNE
}
__device__ __forceinline__ float lo16(unsigned u) { return __uint_as_float(u << 16); }
__device__ __forceinline__ float hi16(unsigned u) { return __uint_as_float(u & 0xFFFF0000u); }

// ---------------- chunked full-range histogram, packed u8, zero global atomics ----------------
__global__ __launch_bounds__(256) void k_hist(
        const int* __restrict__ src, const int* __restrict__ dst,
        unsigned* __restrict__ partial_out, unsigned* __restrict__ partial_in,
        int E, int NP, int Ec) {
    __shared__ unsigned h[NPMAX];
    int tid = threadIdx.x;
    int b = blockIdx.x;
    int c = b & (CH - 1);
    const int* __restrict__ arr = (b < CH) ? src : dst;
    unsigned* __restrict__ outp = ((b < CH) ? partial_out : partial_in) + (size_t)c * NP;
    for (int i = tid; i < NP; i += 256) h[i] = 0;
    __syncthreads();
    int e0 = c * Ec, e1 = min(E, e0 + Ec);
    for (int e = e0 + tid; e < e1; e += 256) {
        int v = arr[e];
        atomicAdd(&h[v >> 2], 1u << ((v & 3) * 8));
    }
    __syncthreads();
    for (int i = tid; i < NP; i += 256) outp[i] = h[i];
}

// ---------------- merge partials: totals + in-place exclusive chunk-prefix ----------------
__global__ void k_merge(unsigned* __restrict__ partial_out, unsigned* __restrict__ partial_in,
                        int* __restrict__ cnt_in, float* __restrict__ norm_out,
                        float* __restrict__ norm_in, int N, int NP) {
    int w = blockIdx.x * blockDim.x + threadIdx.x;
    if (w >= NP) return;
    unsigned run_in = 0, run_out = 0;
    for (int c = 0; c < CH; c++) {
        size_t idx = (size_t)c * NP + w;
        unsigned v = partial_in[idx];
        partial_in[idx] = run_in;
        run_in += v;
        run_out += partial_out[idx];
    }
    #pragma unroll
    for (int j = 0; j < 4; j++) {
        int node = w * 4 + j;
        if (node < N) {
            unsigned di = (run_in  >> (j * 8)) & 255u;
            unsigned dd = (run_out >> (j * 8)) & 255u;
            cnt_in[node]   = (int)di;
            norm_in[node]  = rsqrtf(fmaxf((float)di, 1.0f));
            norm_out[node] = rsqrtf(fmaxf((float)dd, 1.0f));
        }
    }
}

// ---------------- 2-level exclusive scan of cnt_in -> row_start ----------------
__global__ void k_scan_local(const int* __restrict__ cnt, int* __restrict__ excl,
                             int* __restrict__ bsum, int N) {
    __shared__ int s[256];
    int x = threadIdx.x;
    int i = blockIdx.x * 256 + x;
    int v = (i < N) ? cnt[i] : 0;
    s[x] = v;
    __syncthreads();
    for (int off = 1; off < 256; off <<= 1) {
        int t = (x >= off) ? s[x - off] : 0;
        __syncthreads();
        s[x] += t;
        __syncthreads();
    }
    if (i < N) excl[i] = s[x] - v;
    if (x == 255) bsum[blockIdx.x] = s[255];
}

// block 0: scan of block sums; blocks 1..128: pack W0,W1 -> bf16 MFMA B-fragment order
// WF[f][lane][e] with f=nt*4+fi, lane=q*16+c: value = W[k*128+n], n=nt*16+c, k=fi*32+q*8+e
__global__ void k_scan_bsum_prep(int* __restrict__ bsum, int* __restrict__ boff, int nb,
                                 const float* __restrict__ W0, const float* __restrict__ W1,
                                 unsigned short* __restrict__ WF0, unsigned short* __restrict__ WF1) {
    if (blockIdx.x == 0) {
        __shared__ int s[256];
        int x = threadIdx.x;
        int v = (x < nb) ? bsum[x] : 0;
        s[x] = v;
        __syncthreads();
        for (int off = 1; off < 256; off <<= 1) {
            int t = (x >= off) ? s[x - off] : 0;
            __syncthreads();
            s[x] += t;
            __syncthreads();
        }
        if (x < nb) boff[x] = s[x] - v;
    } else {
        int t = ((int)blockIdx.x - 1) * 256 + threadIdx.x;  // 0..32767
        const float* __restrict__ W = (t < 16384) ? W0 : W1;
        unsigned short* __restrict__ WF = (t < 16384) ? WF0 : WF1;
        int tt = t & 16383;
        int f = tt >> 9, l = (tt >> 3) & 63, e = tt & 7;
        int n = (f >> 2) * 16 + (l & 15);
        int k = (f & 3) * 32 + (l >> 4) * 8 + e;
        WF[tt] = f2bf(W[k * 128 + n]);
    }
}

__global__ void k_add_off(int* __restrict__ row_start, const int* __restrict__ boff,
                          float* __restrict__ g, int N) {
    int i = blockIdx.x * blockDim.x + threadIdx.x;
    int stride = gridDim.x * blockDim.x;
    if (i < N) row_start[i] += boff[i >> 8];
    for (int j = i; j < NG * FEAT; j += stride) g[j] = 0.f;  // zero pooled accum
}

// ---------------- chunked CSR fill (LDS cursors, packed u8, u16 csr) + build x0 ----------------
__global__ __launch_bounds__(256) void k_fill_bx(
        const int* __restrict__ src, const int* __restrict__ dst,
        const int* __restrict__ row_start, const unsigned* __restrict__ partial_in,
        unsigned short* __restrict__ csr,
        const int* __restrict__ nid, const int* __restrict__ z,
        const float* __restrict__ emb, const float* __restrict__ zt,
        const float* __restrict__ nout, unsigned short* __restrict__ x,
        int N, int E, int NP, int Ec) {
    if ((int)blockIdx.x < CH) {
        __shared__ unsigned cur[NPMAX];
        int tid = threadIdx.x;
        int c = blockIdx.x;
        const unsigned* __restrict__ pre = partial_in + (size_t)c * NP;
        for (int i = tid; i < NP; i += 256) cur[i] = pre[i];
        __syncthreads();
        int e0 = c * Ec, e1 = min(E, e0 + Ec);
        for (int e = e0 + tid; e < e1; e += 256) {
            int d = dst[e], s = src[e];
            int sh = (d & 3) * 8;
            unsigned t = atomicAdd(&cur[d >> 2], 1u << sh);
            int off = (int)((t >> sh) & 255u);
            csr[row_start[d] + off] = (unsigned short)s;
        }
    } else {
        int tid = ((int)blockIdx.x - CH) * 256 + threadIdx.x;
        int i = tid >> 5, q = tid & 31;
        if (i < N) {
            float4 v;
            if (q < 16) v = ((const float4*)emb)[(size_t)nid[i] * 16 + q];
            else        v = ((const float4*)zt)[(size_t)z[i] * 16 + (q - 16)];
            float w = nout[i];
            ushort4 u;
            u.x = f2bf(v.x * w); u.y = f2bf(v.y * w);
            u.z = f2bf(v.z * w); u.w = f2bf(v.w * w);
            ((ushort4*)x)[(size_t)i * 32 + q] = u;
        }
    }
}

// ---------------- gather core: b128 loads, 16 lanes/node, 8-deep ----------------
#define ACC8(u)                                                                  \
    a0 += lo16(u.x); a1 += hi16(u.x); a2 += lo16(u.y); a3 += hi16(u.y);          \
    a4 += lo16(u.z); a5 += hi16(u.z); a6 += lo16(u.w); a7 += hi16(u.w);

#define GATHER_LOOP                                                              \
    {                                                                            \
        int base = row_start[node];                                              \
        int n = cnt_in[node];                                                    \
        const uint4* xp = (const uint4*)x;  /* row = 16 uint4 */                 \
        for (int j0 = 0; j0 < n; j0 += 16) {                                     \
            int rem = n - j0;                                                    \
            int m = rem < 16 ? rem : 16;                                         \
            int e = (int)csr[base + j0 + (ql < m ? ql : 0)];                     \
            int j = 0;                                                           \
            for (; j + 8 <= m; j += 8) {                                         \
                int s0 = __shfl(e, j + 0, 16), s1 = __shfl(e, j + 1, 16);        \
                int s2 = __shfl(e, j + 2, 16), s3 = __shfl(e, j + 3, 16);        \
                int s4 = __shfl(e, j + 4, 16), s5 = __shfl(e, j + 5, 16);        \
                int s6 = __shfl(e, j + 6, 16), s7 = __shfl(e, j + 7, 16);        \
                uint4 u0 = xp[(size_t)s0 * 16 + ql];                             \
                uint4 u1 = xp[(size_t)s1 * 16 + ql];                             \
                uint4 u2 = xp[(size_t)s2 * 16 + ql];                             \
                uint4 u3 = xp[(size_t)s3 * 16 + ql];                             \
                uint4 u4 = xp[(size_t)s4 * 16 + ql];                             \
                uint4 u5 = xp[(size_t)s5 * 16 + ql];                             \
                uint4 u6 = xp[(size_t)s6 * 16 + ql];                             \
                uint4 u7 = xp[(size_t)s7 * 16 + ql];                             \
                ACC8(u0) ACC8(u1) ACC8(u2) ACC8(u3)                              \
                ACC8(u4) ACC8(u5) ACC8(u6) ACC8(u7)                              \
            }                                                                    \
            for (; j + 4 <= m; j += 4) {                                         \
                int s0 = __shfl(e, j + 0, 16), s1 = __shfl(e, j + 1, 16);        \
                int s2 = __shfl(e, j + 2, 16), s3 = __shfl(e, j + 3, 16);        \
                uint4 u0 = xp[(size_t)s0 * 16 + ql];                             \
                uint4 u1 = xp[(size_t)s1 * 16 + ql];                             \
                uint4 u2 = xp[(size_t)s2 * 16 + ql];                             \
                uint4 u3 = xp[(size_t)s3 * 16 + ql];                             \
                ACC8(u0) ACC8(u1) ACC8(u2) ACC8(u3)                              \
            }                                                                    \
            for (; j < m; j++) {                                                 \
                int s = __shfl(e, j, 16);                                        \
                uint4 u = xp[(size_t)s * 16 + ql];                               \
                ACC8(u)                                                          \
            }                                                                    \
        }                                                                        \
    }

// ---------------- fused gather + MFMA GEMM: y = relu((A_hat x) @ W + b) * nout ----------------
// 64 nodes/block; gather in 4 rounds of 16 nodes (16 lanes/node) straight into As LDS;
// W fragments read per-wave from L2-resident WF (coalesced 16B/lane, no LDS tile).
__global__ __launch_bounds__(256) void k_gather_gemm(
        const unsigned short* __restrict__ x, const float* __restrict__ nin,
        const unsigned short* __restrict__ csr, const int* __restrict__ row_start,
        const int* __restrict__ cnt_in, const unsigned short* __restrict__ WF,
        const float* __restrict__ bias, const float* __restrict__ nout,
        unsigned short* __restrict__ y, int N) {
    __shared__ unsigned short As[64 * LDW];  // 17.4KB -> 8 blocks/CU
    int tid = threadIdx.x;
    int nb = blockIdx.x * 64;
    int ql = tid & 15;
    int nsub = tid >> 4;

    #pragma unroll 1
    for (int r = 0; r < 4; r++) {
        int node = nb + r * 16 + nsub;
        float a0 = 0.f, a1 = 0.f, a2 = 0.f, a3 = 0.f;
        float a4 = 0.f, a5 = 0.f, a6 = 0.f, a7 = 0.f;
        if (node < N) {
            GATHER_LOOP
            float ni = nin[node];
            a0 *= ni; a1 *= ni; a2 *= ni; a3 *= ni;
            a4 *= ni; a5 *= ni; a6 *= ni; a7 *= ni;
        }
        uint4 o;
        o.x = (unsigned)f2bf(a0) | ((unsigned)f2bf(a1) << 16);
        o.y = (unsigned)f2bf(a2) | ((unsigned)f2bf(a3) << 16);
        o.z = (unsigned)f2bf(a4) | ((unsigned)f2bf(a5) << 16);
        o.w = (unsigned)f2bf(a6) | ((unsigned)f2bf(a7) << 16);
        *(uint4*)(As + (r * 16 + nsub) * LDW + ql * 8) = o;
    }
    __syncthreads();

    int lane = tid & 63;
    int m0 = (tid >> 6) * 16;
    int c = lane & 15, q = lane >> 4;

    const unsigned short* ap = As + (m0 + c) * LDW + q * 8;
    bf16x8 fa0 = *(const bf16x8*)(ap);
    bf16x8 fa1 = *(const bf16x8*)(ap + 32);
    bf16x8 fa2 = *(const bf16x8*)(ap + 64);
    bf16x8 fa3 = *(const bf16x8*)(ap + 96);
    const bf16x8* __restrict__ wf = (const bf16x8*)WF;

    #pragma unroll
    for (int nt = 0; nt < 8; nt++) {
        bf16x8 fb0 = wf[(nt * 4 + 0) * 64 + lane];
        bf16x8 fb1 = wf[(nt * 4 + 1) * 64 + lane];
        bf16x8 fb2 = wf[(nt * 4 + 2) * 64 + lane];
        bf16x8 fb3 = wf[(nt * 4 + 3) * 64 + lane];
        float bb = bias[nt * 16 + c];
        f32x4 acc = {bb, bb, bb, bb};
        acc = __builtin_amdgcn_mfma_f32_16x16x32_bf16(fa0, fb0, acc, 0, 0, 0);
        acc = __builtin_amdgcn_mfma_f32_16x16x32_bf16(fa1, fb1, acc, 0, 0, 0);
        acc = __builtin_amdgcn_mfma_f32_16x16x32_bf16(fa2, fb2, acc, 0, 0, 0);
        acc = __builtin_amdgcn_mfma_f32_16x16x32_bf16(fa3, fb3, acc, 0, 0, 0);
        #pragma unroll
        for (int rr = 0; rr < 4; rr++) {
            int row = m0 + q * 4 + rr;
            float s = nout[min(nb + row, N - 1)];
            As[row * LDW + nt * 16 + c] = f2bf(fmaxf(acc[rr], 0.f) * s);
        }
    }
    __syncthreads();

    for (int i = tid; i < 64 * 16; i += 256) {
        int row = i >> 4, seg = i & 15;
        int node = nb + row;
        if (node < N) {
            const ushort4* p = (const ushort4*)(As + row * LDW + seg * 8);
            ushort4* d = (ushort4*)(y + (size_t)node * 128 + seg * 8);
            d[0] = p[0]; d[1] = p[1];
        }
    }
}

// ---------------- fused layer-2 gather + SumPool: g[gid] += (A_hat x)[node] ----------------
// graph_id sorted -> a 16-node block spans few graphs: LDS slot accum, then per-slot
// global fp32 atomics (~2*128 per block). GEMM(W2,b2) commuted past pool into k_head.
__global__ __launch_bounds__(256) void k_gather_pool(
        const unsigned short* __restrict__ x, const float* __restrict__ nin,
        const unsigned short* __restrict__ csr, const int* __restrict__ row_start,
        const int* __restrict__ cnt_in, const int* __restrict__ gid,
        float* __restrict__ g, int N) {
    __shared__ float gl[16][FEAT];  // 8KB
    __shared__ int used;
    int tid = threadIdx.x;
    int nb = blockIdx.x * 16;
    for (int i = tid; i < 16 * FEAT; i += 256) ((float*)gl)[i] = 0.f;
    if (tid == 0) used = 0;
    __syncthreads();

    int ql = tid & 15;
    int node = nb + (tid >> 4);
    int g0 = gid[nb];
    float a0 = 0.f, a1 = 0.f, a2 = 0.f, a3 = 0.f;
    float a4 = 0.f, a5 = 0.f, a6 = 0.f, a7 = 0.f;
    int slot = -1;
    if (node < N) {
        GATHER_LOOP
        float ni = nin[node];
        a0 *= ni; a1 *= ni; a2 *= ni; a3 *= ni;
        a4 *= ni; a5 *= ni; a6 *= ni; a7 *= ni;
        slot = gid[node] - g0;
    }
    if (slot >= 16) {  // rare: >15 graph-id jump inside one 16-node block
        float* p = g + (size_t)(g0 + slot) * FEAT + ql * 8;
        atomicAdd(p + 0, a0); atomicAdd(p + 1, a1);
        atomicAdd(p + 2, a2); atomicAdd(p + 3, a3);
        atomicAdd(p + 4, a4); atomicAdd(p + 5, a5);
        atomicAdd(p + 6, a6); atomicAdd(p + 7, a7);
    } else if (slot >= 0) {
        float* p = &gl[slot][ql * 8];
        atomicAdd(p + 0, a0); atomicAdd(p + 1, a1);
        atomicAdd(p + 2, a2); atomicAdd(p + 3, a3);
        atomicAdd(p + 4, a4); atomicAdd(p + 5, a5);
        atomicAdd(p + 6, a6); atomicAdd(p + 7, a7);
        if (ql == 0) atomicOr(&used, 1 << slot);
    }
    __syncthreads();
    int u = used;
    #pragma unroll
    for (int s0 = 0; s0 < 16; s0 += 2) {
        int s = s0 + (tid >> 7);
        if ((u >> s) & 1) {
            int j = tid & 127;
            atomicAdd(&g[(size_t)(g0 + s) * FEAT + j], gl[s][j]);
        }
    }
}

// ---------------- head: ys = g@W2 + cnt*b2 ; out = relu(ys@l1W+l1b)@l2W+l2b ----------------
__global__ __launch_bounds__(256) void k_head(
        const float* __restrict__ g, const int* __restrict__ gid,
        const float* __restrict__ W2, const float* __restrict__ b2,
        const float* __restrict__ l1W, const float* __restrict__ l1b,
        const float* __restrict__ l2W, const float* __restrict__ l2b,
        float* __restrict__ out, int N) {
    __shared__ float gs[128];
    __shared__ float ys[128];
    __shared__ float hs[128];
    int gi = blockIdx.x, tid = threadIdx.x;

    int lo = 0, hi = N;
    while (lo < hi) { int m = (lo + hi) >> 1; if (gid[m] < gi) lo = m + 1; else hi = m; }
    int s0 = lo;
    lo = 0; hi = N;
    while (lo < hi) { int m = (lo + hi) >> 1; if (gid[m] < gi + 1) lo = m + 1; else hi = m; }
    float cnt = (float)(lo - s0);

    if (tid < 128) gs[tid] = g[(size_t)gi * FEAT + tid];
    __syncthreads();
    if (tid < 128) {
        float a = cnt * b2[tid];
        for (int k = 0; k < 128; k++) a += gs[k] * W2[(size_t)k * 128 + tid];
        ys[tid] = a;
    }
    __syncthreads();
    if (tid < 128) {
        float a = l1b[tid];
        for (int k = 0; k < 128; k++) a += ys[k] * l1W[(size_t)k * 128 + tid];
        hs[tid] = fmaxf(a, 0.f);
    }
    __syncthreads();
    if (tid < 200) {
        float a = l2b[tid];
        for (int k = 0; k < 128; k++) a += hs[k] * l2W[(size_t)k * 200 + tid];
        out[(size_t)gi * 200 + tid] = a;
    }
}

extern "C" void kernel_launch(void* const* d_in, const int* in_sizes, int n_in,
                              void* d_out, int out_size, void* d_ws, size_t ws_size,
                              hipStream_t stream) {
    const int*   nid = (const int*)d_in[0];
    const int*   z   = (const int*)d_in[1];
    const int*   src = (const int*)d_in[2];
    const int*   dst = (const int*)d_in[3];
    const int*   gid = (const int*)d_in[4];
    const float* emb = (const float*)d_in[5];
    const float* zt  = (const float*)d_in[6];
    const float* W0  = (const float*)d_in[7];
    const float* b0  = (const float*)d_in[8];
    const float* W1  = (const float*)d_in[9];
    const float* b1  = (const float*)d_in[10];
    const float* W2  = (const float*)d_in[11];
    const float* b2  = (const float*)d_in[12];
    const float* l1W = (const float*)d_in[13];
    const float* l1b = (const float*)d_in[14];
    const float* l2W = (const float*)d_in[15];
    const float* l2b = (const float*)d_in[16];
    float* out = (float*)d_out;

    const int N = in_sizes[0];
    const int E = in_sizes[2];
    const int NB = (N + 255) / 256;     // scan blocks (<=256 required)
    const int NP = (N + 3) / 4;         // node-quads (<= NPMAX)
    const int Ec = (E + CH - 1) / CH;   // edges per chunk

    // ---- workspace ----
    size_t NA = (size_t)((N + 63) & ~63);
    float* norm_out = (float*)d_ws;                      // NA
    float* norm_in  = norm_out + NA;                     // NA
    float* g        = norm_in + NA;                      // NG*FEAT fp32 pooled accum
    unsigned short* xA  = (unsigned short*)(g + (size_t)NG * FEAT);  // N*128 bf16
    unsigned short* xB  = xA + (size_t)N * FEAT;         // N*128 bf16
    unsigned short* WF0 = xB + (size_t)N * FEAT;         // 128*128 bf16 (fragment order)
    unsigned short* WF1 = WF0 + 128 * 128;               // 128*128 bf16
    int* cnt_in    = (int*)(WF1 + 128 * 128);            // NA
    int* row_start = cnt_in + NA;                        // NA
    int* bsum      = row_start + NA;                     // 256
    int* boff      = bsum + 256;                         // 256
    unsigned* partial_out = (unsigned*)(boff + 256);     // CH*NP
    unsigned* partial_in  = partial_out + (size_t)CH * NP; // CH*NP
    unsigned short* csr = (unsigned short*)(partial_in + (size_t)CH * NP); // E u16

    // ---- atomic-free CSR build + norms + W fragment packs ----
    k_hist<<<2 * CH, 256, 0, stream>>>(src, dst, partial_out, partial_in, E, NP, Ec);
    k_merge<<<(NP + 255) / 256, 256, 0, stream>>>(partial_out, partial_in, cnt_in,
                                                  norm_out, norm_in, N, NP);
    k_scan_local<<<NB, 256, 0, stream>>>(cnt_in, row_start, bsum, N);
    k_scan_bsum_prep<<<1 + 128, 256, 0, stream>>>(bsum, boff, NB, W0, W1, WF0, WF1);
    k_add_off<<<NB, 256, 0, stream>>>(row_start, boff, g, N);
    int XB = (N * 32 + 255) / 256;
    k_fill_bx<<<CH + XB, 256, 0, stream>>>(src, dst, row_start, partial_in, csr,
                                           nid, z, emb, zt, norm_out, xA, N, E, NP, Ec);

    int gg_blocks = (N + 63) / 64;
    int gp_blocks = (N + 15) / 16;

    // layer 0: xA -> xB (fused gather+GEMM)
    k_gather_gemm<<<gg_blocks, 256, 0, stream>>>(xA, norm_in, csr, row_start, cnt_in,
                                                 WF0, b0, norm_out, xB, N);
    // layer 1: xB -> xA
    k_gather_gemm<<<gg_blocks, 256, 0, stream>>>(xB, norm_in, csr, row_start, cnt_in,
                                                 WF1, b1, norm_out, xA, N);
    // layer 2: gather fused with SumPool (GEMM commuted past pool via linearity)
    k_gather_pool<<<gp_blocks, 256, 0, stream>>>(xA, norm_in, csr, row_start, cnt_in,
                                                 gid, g, N);

    // tiny per-graph MLP head
    k_head<<<NG, 256, 0, stream>>>(g, gid, W2, b2, l1W, l1b, l2W, l2b, out, N);
}